// Round 1
// baseline (755.685 us; speedup 1.0000x reference)
//
#include <hip/hip_runtime.h>

#define LAT 128
#define CAP 256   // per-node LDS cache of exp(att) values (edges); fallback recomputes

// ---------------- projection GEMM: C = A(N x 128) @ W(128 x 128), for Wq/Wk/Wv ----
// Block: 256 threads, tile 64 nodes x 64 cols, micro-tile 4x4 (nodes strided by 16).
__global__ __launch_bounds__(256) void proj_kernel(
    const float* __restrict__ A,
    const float* __restrict__ Wq, const float* __restrict__ Wk, const float* __restrict__ Wv,
    float* __restrict__ Cq, float* __restrict__ Ck, float* __restrict__ Cv,
    int N)
{
  __shared__ float eL[64][132];   // +4 pad: float4-aligned, breaks worst bank conflicts
  __shared__ float wL[128][64];
  const int t = threadIdx.x;
  const int n0 = blockIdx.x * 64;
  const int half = blockIdx.y;          // cols [half*64, half*64+64)
  const int mat = blockIdx.z;           // 0=q 1=k 2=v
  const float* W = (mat == 0) ? Wq : (mat == 1) ? Wk : Wv;
  float*       C = (mat == 0) ? Cq : (mat == 1) ? Ck : Cv;

  // stage embeds tile 64x128 (coalesced float4)
  #pragma unroll
  for (int it = 0; it < 8; ++it) {
    int flat = (it * 256 + t) * 4;
    int n = flat >> 7, kk = flat & 127;
    float4 v = make_float4(0.f, 0.f, 0.f, 0.f);
    if (n0 + n < N) v = *(const float4*)(A + (size_t)(n0 + n) * LAT + kk);
    *(float4*)&eL[n][kk] = v;
  }
  // stage weight tile 128x64 (coalesced float4)
  #pragma unroll
  for (int it = 0; it < 8; ++it) {
    int flat = (it * 256 + t) * 4;
    int kk = flat >> 6, c = flat & 63;
    *(float4*)&wL[kk][c] = *(const float4*)(W + (size_t)kk * LAT + half * 64 + c);
  }
  __syncthreads();

  const int nl = t & 15;          // node lane: nodes nl, nl+16, nl+32, nl+48
  const int j0 = (t >> 4) * 4;    // 4 consecutive cols
  float acc[4][4] = {};
  #pragma unroll 8
  for (int kk = 0; kk < 128; kk += 2) {
    float4 w0 = *(float4*)&wL[kk][j0];
    float4 w1 = *(float4*)&wL[kk + 1][j0];
    #pragma unroll
    for (int i = 0; i < 4; ++i) {
      float2 e = *(float2*)&eL[nl + 16 * i][kk];
      acc[i][0] += e.x * w0.x + e.y * w1.x;
      acc[i][1] += e.x * w0.y + e.y * w1.y;
      acc[i][2] += e.x * w0.z + e.y * w1.z;
      acc[i][3] += e.x * w0.w + e.y * w1.w;
    }
  }
  #pragma unroll
  for (int i = 0; i < 4; ++i) {
    int n = n0 + nl + 16 * i;
    if (n < N) {
      float4 o = make_float4(acc[i][0], acc[i][1], acc[i][2], acc[i][3]);
      *(float4*)(C + (size_t)n * LAT + half * 64 + j0) = o;
    }
  }
}

// ---------------- CSR build ----------------
__global__ __launch_bounds__(256) void deg_kernel(const int* __restrict__ rows,
                                                  int* __restrict__ counts, int E) {
  int i = blockIdx.x * 256 + threadIdx.x;
  if (i < E) atomicAdd(&counts[rows[i]], 1);
}

__global__ __launch_bounds__(1024) void scan1_kernel(const int* __restrict__ counts,
                                                     int* __restrict__ starts,
                                                     int* __restrict__ bsums, int N) {
  __shared__ int sh[1024];
  int t = threadIdx.x;
  int i = blockIdx.x * 1024 + t;
  int v = (i < N) ? counts[i] : 0;
  sh[t] = v; __syncthreads();
  for (int off = 1; off < 1024; off <<= 1) {
    int x = (t >= off) ? sh[t - off] : 0;
    __syncthreads();
    sh[t] += x;
    __syncthreads();
  }
  if (i < N) starts[i] = sh[t] - v;           // block-local exclusive
  if (t == 1023) bsums[blockIdx.x] = sh[t];   // block total
}

__global__ __launch_bounds__(1024) void scan2_kernel(int* __restrict__ bsums, int nb) {
  __shared__ int sh[1024];
  int t = threadIdx.x;
  int v = (t < nb) ? bsums[t] : 0;
  sh[t] = v; __syncthreads();
  for (int off = 1; off < 1024; off <<= 1) {
    int x = (t >= off) ? sh[t - off] : 0;
    __syncthreads();
    sh[t] += x;
    __syncthreads();
  }
  if (t < nb) bsums[t] = sh[t] - v;           // exclusive
}

__global__ __launch_bounds__(256) void scan3_kernel(int* __restrict__ starts,
                                                    const int* __restrict__ bsums,
                                                    int* __restrict__ cursor, int N) {
  int i = blockIdx.x * 256 + threadIdx.x;
  if (i < N) {
    int s = starts[i] + bsums[i >> 10];
    starts[i] = s;
    cursor[i] = s;
  }
}

__global__ __launch_bounds__(256) void fill_kernel(const int* __restrict__ rows,
                                                   const int* __restrict__ cols,
                                                   int* __restrict__ cursor,
                                                   int* __restrict__ eidx,
                                                   int* __restrict__ ecol, int E) {
  int i = blockIdx.x * 256 + threadIdx.x;
  if (i < E) {
    int p = atomicAdd(&cursor[rows[i]], 1);
    eidx[p] = i;
    ecol[p] = cols[i];
  }
}

// ---------------- attention: one wave per node ----------------
// lane l owns feature dims {2l, 2l+1}; head h = l>>4 (dims h*32..h*32+31).
// Q was stashed in outRes by proj_kernel; each wave reads only its own row
// before overwriting it with the result.
__global__ __launch_bounds__(256) void attn_kernel(
    const float* __restrict__ Kb, const float* __restrict__ Vb,
    const int* __restrict__ starts, const int* __restrict__ counts,
    const int* __restrict__ eidx, const int* __restrict__ ecol,
    float* __restrict__ outRes, float* __restrict__ outAtt, int N)
{
  __shared__ float expCache[4][CAP * 4];
  const int w = threadIdx.x >> 6;
  const int lane = threadIdx.x & 63;
  const int n = blockIdx.x * 4 + w;
  if (n >= N) return;
  const int h = lane >> 4;
  const int start = starts[n];
  const int deg = counts[n];
  const float2 q = *(const float2*)(outRes + (size_t)n * LAT + lane * 2);

  // pass 1: exp(clip(q.k)) per edge, per head; accumulate denominator
  float denom = 0.f;
  for (int base = 0; base < deg; base += 64) {
    int j = base + lane;
    int c_l = 0;
    if (j < deg) c_l = ecol[start + j];
    int m = deg - base; if (m > 64) m = 64;
    for (int jj = 0; jj < m; ++jj) {
      int c = __shfl(c_l, jj);
      float2 kv = *(const float2*)(Kb + (size_t)c * LAT + lane * 2);
      float s = q.x * kv.x + q.y * kv.y;
      s += __shfl_xor(s, 1); s += __shfl_xor(s, 2);
      s += __shfl_xor(s, 4); s += __shfl_xor(s, 8);   // 16-lane (head) reduce
      s = fminf(fmaxf(s, -10.f), 10.f);
      float ea = __expf(s);
      denom += ea;
      int idx = base + jj;
      if (idx < CAP && (lane & 15) == 0) expCache[w][idx * 4 + h] = ea;
    }
  }
  const float rden = 1.f / (denom + 1e-8f);

  // pass 2: normalize, emit att, accumulate att*V
  float acc0 = 0.f, acc1 = 0.f;
  for (int base = 0; base < deg; base += 64) {
    int j = base + lane;
    int e_l = 0, c_l = 0;
    if (j < deg) { e_l = eidx[start + j]; c_l = ecol[start + j]; }
    int m = deg - base; if (m > 64) m = 64;
    for (int jj = 0; jj < m; ++jj) {
      int c = __shfl(c_l, jj);
      int e = __shfl(e_l, jj);
      int idx = base + jj;
      float ea;
      if (idx < CAP) {
        ea = expCache[w][idx * 4 + h];
      } else {  // rare fallback: recompute
        float2 kv = *(const float2*)(Kb + (size_t)c * LAT + lane * 2);
        float s = q.x * kv.x + q.y * kv.y;
        s += __shfl_xor(s, 1); s += __shfl_xor(s, 2);
        s += __shfl_xor(s, 4); s += __shfl_xor(s, 8);
        s = fminf(fmaxf(s, -10.f), 10.f);
        ea = __expf(s);
      }
      float attn = ea * rden;
      float2 vv = *(const float2*)(Vb + (size_t)c * LAT + lane * 2);
      acc0 += attn * vv.x;
      acc1 += attn * vv.y;
      if ((lane & 15) == 0) outAtt[(size_t)e * 4 + h] = attn;
    }
  }
  float2 r; r.x = acc0; r.y = acc1;
  *(float2*)(outRes + (size_t)n * LAT + lane * 2) = r;
}

// ---------------- launch ----------------
extern "C" void kernel_launch(void* const* d_in, const int* in_sizes, int n_in,
                              void* d_out, int out_size, void* d_ws, size_t ws_size,
                              hipStream_t stream) {
  const float* embeds = (const float*)d_in[0];
  const float* qT = (const float*)d_in[1];
  const float* kT = (const float*)d_in[2];
  const float* vT = (const float*)d_in[3];
  const int* rows = (const int*)d_in[4];
  const int* cols = (const int*)d_in[5];

  if (in_sizes[1] != LAT * LAT) return;   // kernel specialized for latdim=128
  const int N = in_sizes[0] / LAT;
  const int E = in_sizes[4];

  float* outRes = (float*)d_out;                    // [N,128]; temporarily holds Q
  float* outAtt = outRes + (size_t)N * LAT;         // [E,4]

  // workspace carve-up
  char* w = (char*)d_ws;
  size_t need = (size_t)N * LAT * 4 * 2 + (size_t)N * 4 * 3 + 1024 * 4 + (size_t)E * 4 * 2;
  if (ws_size < need) return;                       // loud failure > silent corruption
  float* Kb = (float*)w;      w += (size_t)N * LAT * 4;
  float* Vb = (float*)w;      w += (size_t)N * LAT * 4;
  int* counts = (int*)w;      w += (size_t)N * 4;
  int* starts = (int*)w;      w += (size_t)N * 4;
  int* cursor = (int*)w;      w += (size_t)N * 4;
  int* bsums  = (int*)w;      w += 1024 * 4;
  int* eidx   = (int*)w;      w += (size_t)E * 4;
  int* ecol   = (int*)w;      w += (size_t)E * 4;

  hipMemsetAsync(counts, 0, (size_t)N * 4, stream);

  // per-node projections: Q -> outRes (stash), K/V -> workspace
  dim3 pg((N + 63) / 64, 2, 3);
  proj_kernel<<<pg, 256, 0, stream>>>(embeds, qT, kT, vT, outRes, Kb, Vb, N);

  // CSR of edges bucketed by destination (rows)
  deg_kernel<<<(E + 255) / 256, 256, 0, stream>>>(rows, counts, E);
  int nb = (N + 1023) / 1024;
  scan1_kernel<<<nb, 1024, 0, stream>>>(counts, starts, bsums, N);
  scan2_kernel<<<1, 1024, 0, stream>>>(bsums, nb);
  scan3_kernel<<<(N + 255) / 256, 256, 0, stream>>>(starts, bsums, cursor, N);
  fill_kernel<<<(E + 255) / 256, 256, 0, stream>>>(rows, cols, cursor, eidx, ecol, E);

  // fused per-node attention + normalization + scatter-free aggregation
  attn_kernel<<<(N + 3) / 4, 256, 0, stream>>>(Kb, Vb, starts, counts, eidx, ecol,
                                               outRes, outAtt, N);
}